// Round 9
// baseline (281.578 us; speedup 1.0000x reference)
//
#include <hip/hip_runtime.h>

#define B_  2
#define T_  1024
#define D_  2048
#define NH  16
#define KH  4
#define HD  128
#define TC_ 1024
#define S_  2048

typedef __bf16 bf16x4v __attribute__((ext_vector_type(4)));
typedef __bf16 bf16x8v __attribute__((ext_vector_type(8)));
typedef float  f32x4v  __attribute__((ext_vector_type(4)));

__device__ __forceinline__ void async_copy16(void* lds, const void* g) {
    __builtin_amdgcn_global_load_lds(
        (__attribute__((address_space(1))) void*)g,
        (__attribute__((address_space(3))) void*)lds, 16, 0, 0);
}

// ---------------- prep: x fp32->bf16  +  cache copy/convert (merged) ----------------
__global__ void prep(const float* __restrict__ x, __bf16* __restrict__ xb,
                     const float4* __restrict__ ck, const float4* __restrict__ cv,
                     float* __restrict__ kout, float* __restrict__ vout,
                     __bf16* __restrict__ kb) {
    int bid = blockIdx.x;
    if (bid < 4096) {
        int i = (bid * 256 + threadIdx.x) * 4;
        float4 v = *(const float4*)(x + i);
        bf16x4v o; o[0]=(__bf16)v.x; o[1]=(__bf16)v.y; o[2]=(__bf16)v.z; o[3]=(__bf16)v.w;
        *(bf16x4v*)(xb + i) = o;
    } else {
        int i = (bid - 4096) * 256 + threadIdx.x;   // 262144 total
        int b = i >> 17;
        int r = i & 131071;
        float4 kv = ck[i];
        ((float4*)(kout + (size_t)b * S_ * KH * HD))[r] = kv;
        ((float4*)(vout + (size_t)b * S_ * KH * HD))[r] = cv[i];
        int h4 = r & 31;
        int kh = (r >> 5) & 3;
        int s  = r >> 7;
        bf16x4v o; o[0]=(__bf16)kv.x; o[1]=(__bf16)kv.y; o[2]=(__bf16)kv.z; o[3]=(__bf16)kv.w;
        *(bf16x4v*)(kb + (((size_t)(b * KH + kh) * S_ + s) * HD) + h4 * 4) = o;
    }
}

// ---------------- all weight transposes (merged) ----------------
__global__ void tp_all(const float* __restrict__ wq, const float* __restrict__ wkv,
                       const float* __restrict__ wo, __bf16* __restrict__ wt,
                       __bf16* __restrict__ wot) {
    __shared__ float tile[32][33];
    int bid = blockIdx.x;
    int tx = threadIdx.x, ty = threadIdx.y;
    if (bid < 6144) {
        int zz  = bid >> 8;
        int rem = bid & 255;
        int h0 = (rem & 3) * 32;
        int d0 = (rem >> 2) * 32;
        const float* ip = (zz < 16) ? (wq + (size_t)zz * D_ * HD)
                                    : (wkv + (size_t)(zz - 16) * D_ * HD);
        __bf16* op = wt + (size_t)zz * D_ * HD;
        for (int i = 0; i < 32; i += 8)
            tile[ty + i][tx] = ip[(size_t)(d0 + ty + i) * HD + h0 + tx];
        __syncthreads();
        for (int i = 0; i < 32; i += 8)
            op[(size_t)(h0 + ty + i) * D_ + d0 + tx] = (__bf16)tile[tx][ty + i];
    } else {
        int r2  = bid - 6144;
        int n   = r2 >> 8;
        int rem = r2 & 255;
        int d0 = (rem & 63) * 32;
        int h0 = (rem >> 6) * 32;
        const float* ip = wo + (size_t)n * (HD * D_);
        for (int i = 0; i < 32; i += 8)
            tile[ty + i][tx] = ip[(size_t)(h0 + ty + i) * D_ + d0 + tx];
        __syncthreads();
        for (int i = 0; i < 32; i += 8)
            wot[(size_t)(d0 + ty + i) * (NH * HD) + n * HD + h0 + tx] = (__bf16)tile[tx][ty + i];
    }
}

// v out region fp32 [B][S][K][H] -> vtb bf16 [B][K][H][S]
__global__ void tp_v(const float* __restrict__ vout, __bf16* __restrict__ vtb) {
    __shared__ float tile[32][33];
    int z = blockIdx.z; int b = z / KH, kh = z % KH;
    int h0 = blockIdx.x * 32;
    int s0 = blockIdx.y * 32;
    const float* ip = vout + ((size_t)b * S_ * KH + kh) * HD;
    int tx = threadIdx.x, ty = threadIdx.y;
    for (int i = 0; i < 32; i += 8)
        tile[ty + i][tx] = ip[(size_t)(s0 + ty + i) * (KH * HD) + h0 + tx];
    __syncthreads();
    __bf16* op = vtb + ((size_t)b * KH + kh) * (size_t)HD * S_;
    for (int i = 0; i < 32; i += 8)
        op[(size_t)(h0 + ty + i) * S_ + s0 + tx] = (__bf16)tile[tx][ty + i];
}

// ---------------- QKV GEMM with fused RoPE/scatter epilogue ----------------
__global__ __launch_bounds__(256, 2)
void gemm_qkv(const __bf16* __restrict__ A, const __bf16* __restrict__ BT,
              const int* __restrict__ pos, __bf16* __restrict__ qws,
              float* __restrict__ kout, float* __restrict__ vout,
              __bf16* __restrict__ kb) {
    __shared__ __bf16 As[128 * 64];
    __shared__ __bf16 Bs[128 * 64];
    const int m0 = blockIdx.x * 128, n0 = blockIdx.y * 128;
    const int tid = threadIdx.x;
    const int wave = tid >> 6, lane = tid & 63;
    const int quad = lane >> 4, l16 = lane & 15;
    const int wm = (wave & 1) * 64;
    const int bn0 = (wave >> 1) * 32;          // n-slot base for this wave
    const int lrow = lane >> 3;
    const int lsw  = (lane & 7) ^ (lrow & 7);

    f32x4v acc[4][4];
    for (int i = 0; i < 4; i++)
        for (int j = 0; j < 4; j++)
            acc[i][j] = (f32x4v){0.f, 0.f, 0.f, 0.f};

    const __bf16* Abase = A + (size_t)m0 * D_;
    const __bf16* Bbase = BT + (size_t)n0 * D_;

    for (int k0 = 0; k0 < D_; k0 += 64) {
        for (int j = 0; j < 4; j++) {
            int r = wave * 32 + j * 8;
            async_copy16(As + (size_t)r * 64,
                         Abase + (size_t)(r + lrow) * D_ + k0 + lsw * 8);
            async_copy16(Bs + (size_t)r * 64,
                         Bbase + (size_t)(r + lrow) * D_ + k0 + lsw * 8);
        }
        __syncthreads();
        for (int ks = 0; ks < 2; ks++) {
            const int ch = ((ks * 4 + quad) ^ (l16 & 7)) * 8;
            bf16x8v a[4], b[4];
            for (int i = 0; i < 4; i++)
                a[i] = *(const bf16x8v*)(As + (wm + i * 16 + l16) * 64 + ch);
            for (int j = 0; j < 4; j++) {
                int bn = bn0 + (j >> 1) * 16 + (j & 1) * 64;
                b[j] = *(const bf16x8v*)(Bs + (bn + l16) * 64 + ch);
            }
            for (int i = 0; i < 4; i++)
                for (int j = 0; j < 4; j++)
                    acc[i][j] = __builtin_amdgcn_mfma_f32_16x16x32_bf16(a[i], b[j], acc[i][j], 0, 0, 0);
        }
        __syncthreads();
    }

    const float RFREQ = 9.210340371976184f / 64.0f;   // ln(1e4)/64
    const float qscale = 0.08838834764831845f;        // 128^-0.5
    const int head = blockIdx.y;

    if (head < NH) {
        for (int i = 0; i < 4; i++)
            for (int r = 0; r < 4; r++) {
                int row = m0 + wm + i * 16 + quad * 4 + r;
                float p = (float)pos[row];
                size_t qo = ((size_t)row * NH + head) * HD;
                for (int jp = 0; jp < 2; jp++) {
                    int hh = bn0 + jp * 16 + l16;
                    float ang = p * __expf(-(float)hh * RFREQ);
                    float sn, cs; __sincosf(ang, &sn, &cs);
                    float x1 = acc[i][jp * 2][r], x2 = acc[i][jp * 2 + 1][r];
                    qws[qo + hh]      = (__bf16)((x1 * cs - x2 * sn) * qscale);
                    qws[qo + hh + 64] = (__bf16)((x2 * cs + x1 * sn) * qscale);
                }
            }
    } else if (head < NH + KH) {
        int kh = head - NH;
        for (int i = 0; i < 4; i++)
            for (int r = 0; r < 4; r++) {
                int row = m0 + wm + i * 16 + quad * 4 + r;
                int b = row >> 10, t = row & 1023;
                float p = (float)pos[row];
                size_t ko  = ((size_t)(b * S_ + TC_ + t) * KH + kh) * HD;
                size_t kbo = ((size_t)(b * KH + kh) * S_ + TC_ + t) * HD;
                for (int jp = 0; jp < 2; jp++) {
                    int hh = bn0 + jp * 16 + l16;
                    float ang = p * __expf(-(float)hh * RFREQ);
                    float sn, cs; __sincosf(ang, &sn, &cs);
                    float x1 = acc[i][jp * 2][r], x2 = acc[i][jp * 2 + 1][r];
                    float k1 = x1 * cs - x2 * sn, k2 = x2 * cs + x1 * sn;
                    kout[ko + hh]      = k1;
                    kout[ko + hh + 64] = k2;
                    kb[kbo + hh]      = (__bf16)k1;
                    kb[kbo + hh + 64] = (__bf16)k2;
                }
            }
    } else {
        int kh = head - NH - KH;
        for (int i = 0; i < 4; i++)
            for (int r = 0; r < 4; r++) {
                int row = m0 + wm + i * 16 + quad * 4 + r;
                int b = row >> 10, t = row & 1023;
                size_t vo = ((size_t)(b * S_ + TC_ + t) * KH + kh) * HD;
                for (int j = 0; j < 4; j++) {
                    int h = bn0 + (j >> 1) * 16 + (j & 1) * 64 + l16;
                    vout[vo + h] = acc[i][j][r];
                }
            }
    }
}

// ---------------- 128x128-tile bf16 GEMM, C = A @ BT^T ----------------
__global__ __launch_bounds__(256, 2)
void gemm_bt(const __bf16* __restrict__ A, const __bf16* __restrict__ BT,
             float* __restrict__ C, int ldc) {
    __shared__ __bf16 As[128 * 64];
    __shared__ __bf16 Bs[128 * 64];
    const int m0 = blockIdx.x * 128, n0 = blockIdx.y * 128;
    const int tid = threadIdx.x;
    const int wave = tid >> 6, lane = tid & 63;
    const int quad = lane >> 4, l16 = lane & 15;
    const int wm = (wave & 1) * 64, wn = (wave >> 1) * 64;
    const int lrow = lane >> 3;
    const int lsw  = (lane & 7) ^ (lrow & 7);

    f32x4v acc[4][4];
    for (int i = 0; i < 4; i++)
        for (int j = 0; j < 4; j++)
            acc[i][j] = (f32x4v){0.f, 0.f, 0.f, 0.f};

    const __bf16* Abase = A + (size_t)m0 * D_;
    const __bf16* Bbase = BT + (size_t)n0 * D_;

    for (int k0 = 0; k0 < D_; k0 += 64) {
        for (int j = 0; j < 4; j++) {
            int r = wave * 32 + j * 8;
            async_copy16(As + (size_t)r * 64,
                         Abase + (size_t)(r + lrow) * D_ + k0 + lsw * 8);
            async_copy16(Bs + (size_t)r * 64,
                         Bbase + (size_t)(r + lrow) * D_ + k0 + lsw * 8);
        }
        __syncthreads();
        for (int ks = 0; ks < 2; ks++) {
            const int ch = ((ks * 4 + quad) ^ (l16 & 7)) * 8;
            bf16x8v a[4], b[4];
            for (int i = 0; i < 4; i++)
                a[i] = *(const bf16x8v*)(As + (wm + i * 16 + l16) * 64 + ch);
            for (int j = 0; j < 4; j++)
                b[j] = *(const bf16x8v*)(Bs + (wn + j * 16 + l16) * 64 + ch);
            for (int i = 0; i < 4; i++)
                for (int j = 0; j < 4; j++)
                    acc[i][j] = __builtin_amdgcn_mfma_f32_16x16x32_bf16(a[i], b[j], acc[i][j], 0, 0, 0);
        }
        __syncthreads();
    }
    for (int i = 0; i < 4; i++)
        for (int j = 0; j < 4; j++)
            for (int r = 0; r < 4; r++) {
                int row = m0 + wm + i * 16 + quad * 4 + r;
                int col = n0 + wn + j * 16 + l16;
                C[(size_t)row * ldc + col] = acc[i][j][r];
            }
}

// ---------------- flash attention: 8 waves, wave owns 32 rows x 64 S-cols ----------
// Wave w: rows (w&3)*32..+31, S-cols (w>>2)*64..+63 of each 128x128 score tile.
// Each B-fragment read feeds TWO row-fragments -> K/V LDS-read traffic halves
// (the measured bottleneck: ~640KB ds_read per tile was ~65% of tile time).
// Q in registers (R3-proven layout). Wave pair (w, w+4) holds independent
// online-softmax partials over interleaved S-halves; merged once in LDS at the
// epilogue (no HBM partials). Same grid, HBM traffic, MFMA count as round-1.
__global__ __launch_bounds__(512, 1)
void attn(const __bf16* __restrict__ qws, const __bf16* __restrict__ kb,
          const __bf16* __restrict__ vtb, __bf16* __restrict__ enc) {
    __shared__ __bf16 Ks[128 * 128];
    __shared__ __bf16 Vs[128 * 128];
    __shared__ __bf16 Ps[128 * 128];

    const int t0 = blockIdx.x * 128;
    const int n  = blockIdx.y;
    const int b  = blockIdx.z;
    const int kh = n / (NH / KH);
    const int tid = threadIdx.x, wave = tid >> 6, lane = tid & 63;
    const int quad = lane >> 4, l16 = lane & 15;
    const int wr = (wave & 3) * 32;       // row band
    const int wc = (wave >> 2) * 64;      // S-col half
    const int wm = wave * 16;             // staging row group
    const int arow = lane >> 4;
    const int acol = lane & 15;

    const __bf16* kbase = kb  + ((size_t)(b * KH + kh)) * S_ * HD;
    const __bf16* vbase = vtb + ((size_t)(b * KH + kh)) * (size_t)HD * S_;

    // Q A-fragments in registers: f in {0,1}, row = t0+wr+f*16+l16, chunk ks*4+quad
    bf16x8v qreg[2][4];
#pragma unroll
    for (int f = 0; f < 2; f++) {
        const __bf16* qrow = qws + ((size_t)(b * T_ + t0 + wr + f * 16 + l16) * NH + n) * HD;
#pragma unroll
        for (int ks = 0; ks < 4; ks++)
            qreg[f][ks] = *(const bf16x8v*)(qrow + (ks * 4 + quad) * 8);
    }

    float m_run[2][4], l_run[2][4];
    f32x4v o_acc[2][8];
#pragma unroll
    for (int f = 0; f < 2; f++)
        for (int r = 0; r < 4; r++) { m_run[f][r] = -INFINITY; l_run[f][r] = 0.f; }
#pragma unroll
    for (int f = 0; f < 2; f++)
        for (int j = 0; j < 8; j++) o_acc[f][j] = (f32x4v){0.f, 0.f, 0.f, 0.f};

    const int nS = (TC_ + t0 + 128) >> 7;

    for (int st = 0; st < nS; st++) {
        const int s0 = st * 128;
        {   // K tile [128 s][128 h], swizzled source chunk c^(row&15)
            const __bf16* ktile = kbase + (size_t)s0 * HD;
            for (int jj = 0; jj < 4; jj++) {
                int r0 = wm + jj * 4;
                int row = r0 + arow;
                async_copy16(Ks + (size_t)r0 * 128,
                             ktile + (size_t)row * HD + ((acol ^ (row & 15)) * 8));
            }
        }
        {   // V tile [128 h][128 s], swizzled source chunk c^(row&15)
            const __bf16* vtile = vbase + s0;
            for (int jj = 0; jj < 4; jj++) {
                int r0 = wm + jj * 4;
                int row = r0 + arow;
                async_copy16(Vs + (size_t)r0 * 128,
                             vtile + (size_t)row * S_ + ((acol ^ (row & 15)) * 8));
            }
        }
        __syncthreads();

        // QK^T: 32 rows x 64 cols; each K B-frag feeds both A-frags
        f32x4v sc[2][4];
#pragma unroll
        for (int f = 0; f < 2; f++)
            for (int j = 0; j < 4; j++) sc[f][j] = (f32x4v){0.f, 0.f, 0.f, 0.f};
#pragma unroll
        for (int ks = 0; ks < 4; ks++) {
            int ch = (ks * 4 + quad) ^ l16;
            bf16x8v bb[4];
#pragma unroll
            for (int j = 0; j < 4; j++)
                bb[j] = *(const bf16x8v*)(Ks + (wc + j * 16 + l16) * 128 + ch * 8);
#pragma unroll
            for (int f = 0; f < 2; f++)
#pragma unroll
                for (int j = 0; j < 4; j++)
                    sc[f][j] = __builtin_amdgcn_mfma_f32_16x16x32_bf16(qreg[f][ks], bb[j], sc[f][j], 0, 0, 0);
        }

        // causal mask (diagonal tile only: s0 == TC + t0)
        if (st == nS - 1) {
#pragma unroll
            for (int f = 0; f < 2; f++)
                for (int j = 0; j < 4; j++)
                    for (int r = 0; r < 4; r++) {
                        int row = wr + f * 16 + quad * 4 + r;
                        int col = wc + j * 16 + l16;
                        if (col > row) sc[f][j][r] = -3.0e38f;
                    }
        }

        // online softmax over this wave's 64-col half (16-lane reduce), P -> LDS
#pragma unroll
        for (int f = 0; f < 2; f++) {
            for (int r = 0; r < 4; r++) {
                float mx = sc[f][0][r];
                for (int j = 1; j < 4; j++) mx = fmaxf(mx, sc[f][j][r]);
                for (int off = 8; off >= 1; off >>= 1) mx = fmaxf(mx, __shfl_xor(mx, off, 64));
                mx = fmaxf(mx, m_run[f][r]);
                float alpha = __expf(m_run[f][r] - mx);
                m_run[f][r] = mx;
                float s = 0.f;
                for (int j = 0; j < 4; j++) {
                    float pv = __expf(sc[f][j][r] - mx);
                    sc[f][j][r] = pv;
                    s += pv;
                }
                for (int off = 8; off >= 1; off >>= 1) s += __shfl_xor(s, off, 64);
                l_run[f][r] = l_run[f][r] * alpha + s;
                for (int j = 0; j < 8; j++) o_acc[f][j][r] *= alpha;
            }
            // P quadrant -> LDS, global s-chunk = wc/8 + j*2 + (l16>>3), slot ^(row&15)
            for (int j = 0; j < 4; j++)
                for (int r = 0; r < 4; r++) {
                    int row = wr + f * 16 + quad * 4 + r;
                    int c = ((wc >> 3) + j * 2 + (l16 >> 3)) ^ (row & 15);
                    Ps[row * 128 + c * 8 + (l16 & 7)] = (__bf16)sc[f][j][r];
                }
        }
        __syncthreads();

        // PV: o_acc += P[rows, own-half] @ V[own-half, 0..127]; V B-frags shared across f
#pragma unroll
        for (int ks = 0; ks < 2; ks++) {
            int gch = (wc >> 3) + ks * 4 + quad;    // global s-chunk in own half
            bf16x8v a0, a1;
            {
                int row0 = wr + l16, row1 = wr + 16 + l16;
                a0 = *(const bf16x8v*)(Ps + row0 * 128 + (gch ^ (row0 & 15)) * 8);
                a1 = *(const bf16x8v*)(Ps + row1 * 128 + (gch ^ (row1 & 15)) * 8);
            }
            bf16x8v bb[8];
#pragma unroll
            for (int j = 0; j < 8; j++)
                bb[j] = *(const bf16x8v*)(Vs + (j * 16 + l16) * 128 + (gch ^ l16) * 8);
#pragma unroll
            for (int j = 0; j < 8; j++) {
                o_acc[0][j] = __builtin_amdgcn_mfma_f32_16x16x32_bf16(a0, bb[j], o_acc[0][j], 0, 0, 0);
                o_acc[1][j] = __builtin_amdgcn_mfma_f32_16x16x32_bf16(a1, bb[j], o_acc[1][j], 0, 0, 0);
            }
        }
        __syncthreads();
    }

    // ---- epilogue: merge wave-pair partials (w, w+4) in LDS, then write enc ----
    if (wave >= 4) {
        int w4 = wave - 4;
        float* obuf = (float*)(w4 < 2 ? Ks : Vs) + (size_t)(w4 & 1) * 4096;
#pragma unroll
        for (int f = 0; f < 2; f++)
            for (int j = 0; j < 8; j++) {
                int e = f * 8 + j;
                *(f32x4v*)(obuf + (size_t)lane * 64 + ((e ^ (lane & 15)) << 2)) = o_acc[f][j];
            }
        float* mlb = (float*)Ps;
        if (l16 == 0)
            for (int f = 0; f < 2; f++)
                for (int r = 0; r < 4; r++) {
                    int row = w4 * 32 + f * 16 + quad * 4 + r;
                    mlb[row * 2]     = m_run[f][r];
                    mlb[row * 2 + 1] = l_run[f][r];
                }
    }
    __syncthreads();
    if (wave < 4) {
        float* obuf = (float*)(wave < 2 ? Ks : Vs) + (size_t)(wave & 1) * 4096;
        float* mlb = (float*)Ps;
#pragma unroll
        for (int f = 0; f < 2; f++)
            for (int r = 0; r < 4; r++) {
                int lrow = wr + f * 16 + quad * 4 + r;
                float m1 = mlb[lrow * 2], l1 = mlb[lrow * 2 + 1];
                float m0 = m_run[f][r], l0 = l_run[f][r];
                float M = fmaxf(m0, m1);
                float a0 = __expf(m0 - M), a1 = __expf(m1 - M);
                float inv = 1.f / (l0 * a0 + l1 * a1);
                size_t eo = ((size_t)(b * T_ + t0 + lrow) * NH + n) * HD;
                for (int j = 0; j < 8; j++) {
                    int e = f * 8 + j;
                    f32x4v o1 = *(const f32x4v*)(obuf + (size_t)lane * 64 + ((e ^ (lane & 15)) << 2));
                    float v = (o_acc[f][j][r] * a0 + o1[r] * a1) * inv;
                    enc[eo + j * 16 + l16] = (__bf16)v;
                }
            }
    }
}

extern "C" void kernel_launch(void* const* d_in, const int* in_sizes, int n_in,
                              void* d_out, int out_size, void* d_ws, size_t ws_size,
                              hipStream_t stream) {
    const float* x       = (const float*)d_in[0];
    const int*   pos     = (const int*)d_in[1];
    const float* cache_k = (const float*)d_in[3];
    const float* cache_v = (const float*)d_in[4];
    const float* w_q     = (const float*)d_in[5];
    const float* w_kv    = (const float*)d_in[6];
    const float* w_out   = (const float*)d_in[7];

    float* out  = (float*)d_out;
    float* kout = out  + (size_t)B_ * T_ * D_;
    float* vout = kout + (size_t)B_ * S_ * KH * HD;

    char* ws = (char*)d_ws;
    __bf16* xb   = (__bf16*)ws;  ws += (size_t)B_ * T_ * D_ * 2;
    __bf16* wt   = (__bf16*)ws;  ws += (size_t)3072 * D_ * 2;
    __bf16* wot  = (__bf16*)ws;  ws += (size_t)D_ * NH * HD * 2;
    __bf16* qws  = (__bf16*)ws;  ws += (size_t)B_ * T_ * NH * HD * 2;
    __bf16* kbuf = (__bf16*)ws;  ws += (size_t)B_ * S_ * KH * HD * 2;
    __bf16* vtb  = (__bf16*)ws;  ws += (size_t)B_ * S_ * KH * HD * 2;
    __bf16* enc  = (__bf16*)ws;

    prep<<<5120, 256, 0, stream>>>(x, xb, (const float4*)cache_k, (const float4*)cache_v,
                                   kout, vout, kbuf);
    tp_all<<<10240, dim3(32, 8), 0, stream>>>(w_q, w_kv, w_out, wt, wot);
    gemm_qkv<<<dim3(16, 24), 256, 0, stream>>>(xb, wt, pos, qws, kout, vout, kbuf);
    tp_v<<<dim3(4, 64, 8), dim3(32, 8), 0, stream>>>(vout, vtb);
    attn<<<dim3(8, 16, 2), 512, 0, stream>>>(qws, kbuf, vtb, enc);
    gemm_bt<<<dim3(16, 16), 256, 0, stream>>>(enc, wot, out, 2048);
}

// Round 10
// 272.731 us; speedup vs baseline: 1.0324x; 1.0324x over previous
//
#include <hip/hip_runtime.h>

#define B_  2
#define T_  1024
#define D_  2048
#define NH  16
#define KH  4
#define HD  128
#define TC_ 1024
#define S_  2048

typedef __bf16 bf16x4v __attribute__((ext_vector_type(4)));
typedef __bf16 bf16x8v __attribute__((ext_vector_type(8)));
typedef float  f32x4v  __attribute__((ext_vector_type(4)));

__device__ __forceinline__ void async_copy16(void* lds, const void* g) {
    __builtin_amdgcn_global_load_lds(
        (__attribute__((address_space(1))) void*)g,
        (__attribute__((address_space(3))) void*)lds, 16, 0, 0);
}

// ---------------- prep: x fp32->bf16  +  cache copy/convert (merged) ----------------
__global__ void prep(const float* __restrict__ x, __bf16* __restrict__ xb,
                     const float4* __restrict__ ck, const float4* __restrict__ cv,
                     float* __restrict__ kout, float* __restrict__ vout,
                     __bf16* __restrict__ kb) {
    int bid = blockIdx.x;
    if (bid < 4096) {
        int i = (bid * 256 + threadIdx.x) * 4;
        float4 v = *(const float4*)(x + i);
        bf16x4v o; o[0]=(__bf16)v.x; o[1]=(__bf16)v.y; o[2]=(__bf16)v.z; o[3]=(__bf16)v.w;
        *(bf16x4v*)(xb + i) = o;
    } else {
        int i = (bid - 4096) * 256 + threadIdx.x;   // 262144 total
        int b = i >> 17;
        int r = i & 131071;
        float4 kv = ck[i];
        ((float4*)(kout + (size_t)b * S_ * KH * HD))[r] = kv;
        ((float4*)(vout + (size_t)b * S_ * KH * HD))[r] = cv[i];
        int h4 = r & 31;
        int kh = (r >> 5) & 3;
        int s  = r >> 7;
        bf16x4v o; o[0]=(__bf16)kv.x; o[1]=(__bf16)kv.y; o[2]=(__bf16)kv.z; o[3]=(__bf16)kv.w;
        *(bf16x4v*)(kb + (((size_t)(b * KH + kh) * S_ + s) * HD) + h4 * 4) = o;
    }
}

// ---------------- all weight transposes (merged) ----------------
__global__ void tp_all(const float* __restrict__ wq, const float* __restrict__ wkv,
                       const float* __restrict__ wo, __bf16* __restrict__ wt,
                       __bf16* __restrict__ wot) {
    __shared__ float tile[32][33];
    int bid = blockIdx.x;
    int tx = threadIdx.x, ty = threadIdx.y;
    if (bid < 6144) {
        int zz  = bid >> 8;
        int rem = bid & 255;
        int h0 = (rem & 3) * 32;
        int d0 = (rem >> 2) * 32;
        const float* ip = (zz < 16) ? (wq + (size_t)zz * D_ * HD)
                                    : (wkv + (size_t)(zz - 16) * D_ * HD);
        __bf16* op = wt + (size_t)zz * D_ * HD;
        for (int i = 0; i < 32; i += 8)
            tile[ty + i][tx] = ip[(size_t)(d0 + ty + i) * HD + h0 + tx];
        __syncthreads();
        for (int i = 0; i < 32; i += 8)
            op[(size_t)(h0 + ty + i) * D_ + d0 + tx] = (__bf16)tile[tx][ty + i];
    } else {
        int r2  = bid - 6144;
        int n   = r2 >> 8;
        int rem = r2 & 255;
        int d0 = (rem & 63) * 32;
        int h0 = (rem >> 6) * 32;
        const float* ip = wo + (size_t)n * (HD * D_);
        for (int i = 0; i < 32; i += 8)
            tile[ty + i][tx] = ip[(size_t)(h0 + ty + i) * D_ + d0 + tx];
        __syncthreads();
        for (int i = 0; i < 32; i += 8)
            wot[(size_t)(d0 + ty + i) * (NH * HD) + n * HD + h0 + tx] = (__bf16)tile[tx][ty + i];
    }
}

// v out region fp32 [B][S][K][H] -> vtb bf16 [B][K][H][S]
__global__ void tp_v(const float* __restrict__ vout, __bf16* __restrict__ vtb) {
    __shared__ float tile[32][33];
    int z = blockIdx.z; int b = z / KH, kh = z % KH;
    int h0 = blockIdx.x * 32;
    int s0 = blockIdx.y * 32;
    const float* ip = vout + ((size_t)b * S_ * KH + kh) * HD;
    int tx = threadIdx.x, ty = threadIdx.y;
    for (int i = 0; i < 32; i += 8)
        tile[ty + i][tx] = ip[(size_t)(s0 + ty + i) * (KH * HD) + h0 + tx];
    __syncthreads();
    __bf16* op = vtb + ((size_t)b * KH + kh) * (size_t)HD * S_;
    for (int i = 0; i < 32; i += 8)
        op[(size_t)(h0 + ty + i) * S_ + s0 + tx] = (__bf16)tile[tx][ty + i];
}

// ---------------- QKV GEMM with fused RoPE/scatter epilogue (XCD-swizzled) ---------
// 1-D grid of 384 blocks; swz = (bid%8)*48 + bid/8 keeps each XCD on a contiguous
// run of m-tiles (same B-panel reused within one XCD's L2).
__global__ __launch_bounds__(256, 2)
void gemm_qkv(const __bf16* __restrict__ A, const __bf16* __restrict__ BT,
              const int* __restrict__ pos, __bf16* __restrict__ qws,
              float* __restrict__ kout, float* __restrict__ vout,
              __bf16* __restrict__ kb) {
    __shared__ __bf16 As[128 * 64];
    __shared__ __bf16 Bs[128 * 64];
    const int swz = (blockIdx.x & 7) * 48 + (blockIdx.x >> 3);
    const int m0 = (swz & 15) * 128;
    const int head = swz >> 4;
    const int n0 = head * 128;
    const int tid = threadIdx.x;
    const int wave = tid >> 6, lane = tid & 63;
    const int quad = lane >> 4, l16 = lane & 15;
    const int wm = (wave & 1) * 64;
    const int bn0 = (wave >> 1) * 32;          // n-slot base for this wave
    const int lrow = lane >> 3;
    const int lsw  = (lane & 7) ^ (lrow & 7);

    f32x4v acc[4][4];
    for (int i = 0; i < 4; i++)
        for (int j = 0; j < 4; j++)
            acc[i][j] = (f32x4v){0.f, 0.f, 0.f, 0.f};

    const __bf16* Abase = A + (size_t)m0 * D_;
    const __bf16* Bbase = BT + (size_t)n0 * D_;

    for (int k0 = 0; k0 < D_; k0 += 64) {
        for (int j = 0; j < 4; j++) {
            int r = wave * 32 + j * 8;
            async_copy16(As + (size_t)r * 64,
                         Abase + (size_t)(r + lrow) * D_ + k0 + lsw * 8);
            async_copy16(Bs + (size_t)r * 64,
                         Bbase + (size_t)(r + lrow) * D_ + k0 + lsw * 8);
        }
        __syncthreads();
        for (int ks = 0; ks < 2; ks++) {
            const int ch = ((ks * 4 + quad) ^ (l16 & 7)) * 8;
            bf16x8v a[4], b[4];
            for (int i = 0; i < 4; i++)
                a[i] = *(const bf16x8v*)(As + (wm + i * 16 + l16) * 64 + ch);
            for (int j = 0; j < 4; j++) {
                int bn = bn0 + (j >> 1) * 16 + (j & 1) * 64;
                b[j] = *(const bf16x8v*)(Bs + (bn + l16) * 64 + ch);
            }
            for (int i = 0; i < 4; i++)
                for (int j = 0; j < 4; j++)
                    acc[i][j] = __builtin_amdgcn_mfma_f32_16x16x32_bf16(a[i], b[j], acc[i][j], 0, 0, 0);
        }
        __syncthreads();
    }

    const float RFREQ = 9.210340371976184f / 64.0f;   // ln(1e4)/64
    const float qscale = 0.08838834764831845f;        // 128^-0.5

    if (head < NH) {
        for (int i = 0; i < 4; i++)
            for (int r = 0; r < 4; r++) {
                int row = m0 + wm + i * 16 + quad * 4 + r;
                float p = (float)pos[row];
                size_t qo = ((size_t)row * NH + head) * HD;
                for (int jp = 0; jp < 2; jp++) {
                    int hh = bn0 + jp * 16 + l16;
                    float ang = p * __expf(-(float)hh * RFREQ);
                    float sn, cs; __sincosf(ang, &sn, &cs);
                    float x1 = acc[i][jp * 2][r], x2 = acc[i][jp * 2 + 1][r];
                    qws[qo + hh]      = (__bf16)((x1 * cs - x2 * sn) * qscale);
                    qws[qo + hh + 64] = (__bf16)((x2 * cs + x1 * sn) * qscale);
                }
            }
    } else if (head < NH + KH) {
        int kh = head - NH;
        for (int i = 0; i < 4; i++)
            for (int r = 0; r < 4; r++) {
                int row = m0 + wm + i * 16 + quad * 4 + r;
                int b = row >> 10, t = row & 1023;
                float p = (float)pos[row];
                size_t ko  = ((size_t)(b * S_ + TC_ + t) * KH + kh) * HD;
                size_t kbo = ((size_t)(b * KH + kh) * S_ + TC_ + t) * HD;
                for (int jp = 0; jp < 2; jp++) {
                    int hh = bn0 + jp * 16 + l16;
                    float ang = p * __expf(-(float)hh * RFREQ);
                    float sn, cs; __sincosf(ang, &sn, &cs);
                    float x1 = acc[i][jp * 2][r], x2 = acc[i][jp * 2 + 1][r];
                    float k1 = x1 * cs - x2 * sn, k2 = x2 * cs + x1 * sn;
                    kout[ko + hh]      = k1;
                    kout[ko + hh + 64] = k2;
                    kb[kbo + hh]      = (__bf16)k1;
                    kb[kbo + hh + 64] = (__bf16)k2;
                }
            }
    } else {
        int kh = head - NH - KH;
        for (int i = 0; i < 4; i++)
            for (int r = 0; r < 4; r++) {
                int row = m0 + wm + i * 16 + quad * 4 + r;
                int b = row >> 10, t = row & 1023;
                size_t vo = ((size_t)(b * S_ + TC_ + t) * KH + kh) * HD;
                for (int j = 0; j < 4; j++) {
                    int h = bn0 + (j >> 1) * 16 + (j & 1) * 64 + l16;
                    vout[vo + h] = acc[i][j][r];
                }
            }
    }
}

// ---------------- 128x128-tile bf16 GEMM, C = A @ BT^T (XCD-swizzled) ----------------
__global__ __launch_bounds__(256, 2)
void gemm_bt(const __bf16* __restrict__ A, const __bf16* __restrict__ BT,
             float* __restrict__ C, int ldc) {
    __shared__ __bf16 As[128 * 64];
    __shared__ __bf16 Bs[128 * 64];
    const int swz = (blockIdx.x & 7) * 32 + (blockIdx.x >> 3);
    const int m0 = (swz & 15) * 128, n0 = (swz >> 4) * 128;
    const int tid = threadIdx.x;
    const int wave = tid >> 6, lane = tid & 63;
    const int quad = lane >> 4, l16 = lane & 15;
    const int wm = (wave & 1) * 64, wn = (wave >> 1) * 64;
    const int lrow = lane >> 3;
    const int lsw  = (lane & 7) ^ (lrow & 7);

    f32x4v acc[4][4];
    for (int i = 0; i < 4; i++)
        for (int j = 0; j < 4; j++)
            acc[i][j] = (f32x4v){0.f, 0.f, 0.f, 0.f};

    const __bf16* Abase = A + (size_t)m0 * D_;
    const __bf16* Bbase = BT + (size_t)n0 * D_;

    for (int k0 = 0; k0 < D_; k0 += 64) {
        for (int j = 0; j < 4; j++) {
            int r = wave * 32 + j * 8;
            async_copy16(As + (size_t)r * 64,
                         Abase + (size_t)(r + lrow) * D_ + k0 + lsw * 8);
            async_copy16(Bs + (size_t)r * 64,
                         Bbase + (size_t)(r + lrow) * D_ + k0 + lsw * 8);
        }
        __syncthreads();
        for (int ks = 0; ks < 2; ks++) {
            const int ch = ((ks * 4 + quad) ^ (l16 & 7)) * 8;
            bf16x8v a[4], b[4];
            for (int i = 0; i < 4; i++)
                a[i] = *(const bf16x8v*)(As + (wm + i * 16 + l16) * 64 + ch);
            for (int j = 0; j < 4; j++)
                b[j] = *(const bf16x8v*)(Bs + (wn + j * 16 + l16) * 64 + ch);
            for (int i = 0; i < 4; i++)
                for (int j = 0; j < 4; j++)
                    acc[i][j] = __builtin_amdgcn_mfma_f32_16x16x32_bf16(a[i], b[j], acc[i][j], 0, 0, 0);
        }
        __syncthreads();
    }
    for (int i = 0; i < 4; i++)
        for (int j = 0; j < 4; j++)
            for (int r = 0; r < 4; r++) {
                int row = m0 + wm + i * 16 + quad * 4 + r;
                int col = n0 + wn + j * 16 + l16;
                C[(size_t)row * ldc + col] = acc[i][j][r];
            }
}

// ---------------- flash attention (8 waves, XOR-swizzled LDS) — round-1 proven ----
__global__ __launch_bounds__(512, 1)
void attn(const __bf16* __restrict__ qws, const __bf16* __restrict__ kb,
          const __bf16* __restrict__ vtb, __bf16* __restrict__ enc) {
    __shared__ __bf16 Qs[128 * 128];
    __shared__ __bf16 Ks[128 * 128];
    __shared__ __bf16 Vs[128 * 128];
    __shared__ __bf16 Ps[128 * 128];

    const int t0 = blockIdx.x * 128;
    const int n  = blockIdx.y;
    const int b  = blockIdx.z;
    const int kh = n / (NH / KH);
    const int tid = threadIdx.x, wave = tid >> 6, lane = tid & 63;
    const int quad = lane >> 4, l16 = lane & 15;
    const int wm = wave * 16;
    const int arow = lane >> 4;
    const int acol = lane & 15;

    // Q tile [128 t][128 h], swizzled source
    {
        const __bf16* qtile = qws + ((size_t)(b * T_ + t0) * NH + n) * HD;
        for (int jj = 0; jj < 4; jj++) {
            int r0 = wm + jj * 4;
            int row = r0 + arow;
            async_copy16(Qs + (size_t)r0 * 128,
                         qtile + (size_t)row * (NH * HD) + ((acol ^ (row & 15)) * 8));
        }
    }

    float m_run[4], l_run[4];
    f32x4v o_acc[8];
    for (int r = 0; r < 4; r++) { m_run[r] = -INFINITY; l_run[r] = 0.f; }
    for (int j = 0; j < 8; j++) o_acc[j] = (f32x4v){0.f, 0.f, 0.f, 0.f};

    const int nS = (TC_ + t0 + 128) >> 7;
    const __bf16* kbase = kb  + ((size_t)(b * KH + kh)) * S_ * HD;
    const __bf16* vbase = vtb + ((size_t)(b * KH + kh)) * (size_t)HD * S_;

    for (int st = 0; st < nS; st++) {
        const int s0 = st * 128;
        {
            const __bf16* ktile = kbase + (size_t)s0 * HD;
            for (int jj = 0; jj < 4; jj++) {
                int r0 = wm + jj * 4;
                int row = r0 + arow;
                async_copy16(Ks + (size_t)r0 * 128,
                             ktile + (size_t)row * HD + ((acol ^ (row & 15)) * 8));
            }
        }
        {
            const __bf16* vtile = vbase + s0;
            for (int jj = 0; jj < 4; jj++) {
                int r0 = wm + jj * 4;
                int row = r0 + arow;
                async_copy16(Vs + (size_t)r0 * 128,
                             vtile + (size_t)row * S_ + ((acol ^ (row & 15)) * 8));
            }
        }
        __syncthreads();

        // QK^T: this wave's 16 rows x 128 cols
        f32x4v sc[8];
        for (int j = 0; j < 8; j++) sc[j] = (f32x4v){0.f, 0.f, 0.f, 0.f};
        for (int ks = 0; ks < 4; ks++) {
            int ch = (ks * 4 + quad) ^ l16;
            bf16x8v a = *(const bf16x8v*)(Qs + (wm + l16) * 128 + ch * 8);
            bf16x8v bb[8];
            for (int j = 0; j < 8; j++)
                bb[j] = *(const bf16x8v*)(Ks + (j * 16 + l16) * 128 + ch * 8);
            for (int j = 0; j < 8; j++)
                sc[j] = __builtin_amdgcn_mfma_f32_16x16x32_bf16(a, bb[j], sc[j], 0, 0, 0);
        }

        // causal mask (diagonal tile only: s0 == TC + t0)
        if (st == nS - 1) {
            for (int j = 0; j < 8; j++)
                for (int r = 0; r < 4; r++) {
                    int row = wm + quad * 4 + r;
                    int col = j * 16 + l16;
                    if (col > row) sc[j][r] = -3.0e38f;
                }
        }

        // online softmax
        for (int r = 0; r < 4; r++) {
            float mx = sc[0][r];
            for (int j = 1; j < 8; j++) mx = fmaxf(mx, sc[j][r]);
            for (int off = 8; off >= 1; off >>= 1) mx = fmaxf(mx, __shfl_xor(mx, off, 64));
            mx = fmaxf(mx, m_run[r]);
            float alpha = __expf(m_run[r] - mx);
            m_run[r] = mx;
            float s = 0.f;
            for (int j = 0; j < 8; j++) {
                float pv = __expf(sc[j][r] - mx);
                sc[j][r] = pv;
                s += pv;
            }
            for (int off = 8; off >= 1; off >>= 1) s += __shfl_xor(s, off, 64);
            l_run[r] = l_run[r] * alpha + s;
            for (int j = 0; j < 8; j++) o_acc[j][r] *= alpha;
        }

        // P -> LDS (C-layout -> A-layout), swizzled chunks
        for (int j = 0; j < 8; j++)
            for (int r = 0; r < 4; r++) {
                int row = wm + quad * 4 + r;
                int c = (j * 2 + (l16 >> 3)) ^ (row & 15);
                Ps[row * 128 + c * 8 + (l16 & 7)] = (__bf16)sc[j][r];
            }
        __syncthreads();

        // PV: o_acc += P @ V
        for (int ks = 0; ks < 4; ks++) {
            int ch = (ks * 4 + quad) ^ l16;
            bf16x8v a = *(const bf16x8v*)(Ps + (wm + l16) * 128 + ch * 8);
            bf16x8v bb[8];
            for (int j = 0; j < 8; j++)
                bb[j] = *(const bf16x8v*)(Vs + (j * 16 + l16) * 128 + ch * 8);
            for (int j = 0; j < 8; j++)
                o_acc[j] = __builtin_amdgcn_mfma_f32_16x16x32_bf16(a, bb[j], o_acc[j], 0, 0, 0);
        }
        __syncthreads();
    }

    // epilogue: enc[b,t,n,h] bf16
    for (int r = 0; r < 4; r++) {
        float inv = 1.0f / l_run[r];
        int row = wm + quad * 4 + r;
        for (int j = 0; j < 8; j++) {
            int col = j * 16 + l16;
            enc[((size_t)(b * T_ + t0 + row) * NH + n) * HD + col] =
                (__bf16)(o_acc[j][r] * inv);
        }
    }
}

extern "C" void kernel_launch(void* const* d_in, const int* in_sizes, int n_in,
                              void* d_out, int out_size, void* d_ws, size_t ws_size,
                              hipStream_t stream) {
    const float* x       = (const float*)d_in[0];
    const int*   pos     = (const int*)d_in[1];
    const float* cache_k = (const float*)d_in[3];
    const float* cache_v = (const float*)d_in[4];
    const float* w_q     = (const float*)d_in[5];
    const float* w_kv    = (const float*)d_in[6];
    const float* w_out   = (const float*)d_in[7];

    float* out  = (float*)d_out;
    float* kout = out  + (size_t)B_ * T_ * D_;
    float* vout = kout + (size_t)B_ * S_ * KH * HD;

    char* ws = (char*)d_ws;
    __bf16* xb   = (__bf16*)ws;  ws += (size_t)B_ * T_ * D_ * 2;
    __bf16* wt   = (__bf16*)ws;  ws += (size_t)3072 * D_ * 2;
    __bf16* wot  = (__bf16*)ws;  ws += (size_t)D_ * NH * HD * 2;
    __bf16* qws  = (__bf16*)ws;  ws += (size_t)B_ * T_ * NH * HD * 2;
    __bf16* kbuf = (__bf16*)ws;  ws += (size_t)B_ * S_ * KH * HD * 2;
    __bf16* vtb  = (__bf16*)ws;  ws += (size_t)B_ * S_ * KH * HD * 2;
    __bf16* enc  = (__bf16*)ws;

    prep<<<5120, 256, 0, stream>>>(x, xb, (const float4*)cache_k, (const float4*)cache_v,
                                   kout, vout, kbuf);
    tp_all<<<10240, dim3(32, 8), 0, stream>>>(w_q, w_kv, w_out, wt, wot);
    gemm_qkv<<<384, 256, 0, stream>>>(xb, wt, pos, qws, kout, vout, kbuf);
    tp_v<<<dim3(4, 64, 8), dim3(32, 8), 0, stream>>>(vout, vtb);
    attn<<<dim3(8, 16, 2), 512, 0, stream>>>(qws, kbuf, vtb, enc);
    gemm_bt<<<256, 256, 0, stream>>>(enc, wot, out, 2048);
}

// Round 11
// 266.628 us; speedup vs baseline: 1.0561x; 1.0229x over previous
//
#include <hip/hip_runtime.h>

#define B_  2
#define T_  1024
#define D_  2048
#define NH  16
#define KH  4
#define HD  128
#define TC_ 1024
#define S_  2048

typedef __bf16 bf16x4v __attribute__((ext_vector_type(4)));
typedef __bf16 bf16x8v __attribute__((ext_vector_type(8)));
typedef float  f32x4v  __attribute__((ext_vector_type(4)));

__device__ __forceinline__ void async_copy16(void* lds, const void* g) {
    __builtin_amdgcn_global_load_lds(
        (__attribute__((address_space(1))) void*)g,
        (__attribute__((address_space(3))) void*)lds, 16, 0, 0);
}

// ---------------- prep_all: x cvt + cache copy + weight transposes + cache-V^T ----
// blocks [0,4096): x fp32->bf16
// blocks [4096,5120): cache copy (fp32 exact) + bf16 K-cache
// blocks [5120,15360): weight transposes (wq/wkv then wout)
// blocks [15360,16384): cache half of V transpose: cache_v -> vtb bf16 [B][K][H][S]
__global__ void prep_all(const float* __restrict__ x, __bf16* __restrict__ xb,
                         const float4* __restrict__ ck, const float4* __restrict__ cv,
                         float* __restrict__ kout, float* __restrict__ vout,
                         __bf16* __restrict__ kb,
                         const float* __restrict__ wq, const float* __restrict__ wkv,
                         const float* __restrict__ wo, __bf16* __restrict__ wt,
                         __bf16* __restrict__ wot, __bf16* __restrict__ vtb) {
    __shared__ float tile[32][33];
    const int bid = blockIdx.x;
    const int tx = threadIdx.x, ty = threadIdx.y;
    const int tid = ty * 32 + tx;

    if (bid < 4096) {
        int i = (bid * 256 + tid) * 4;
        float4 v = *(const float4*)(x + i);
        bf16x4v o; o[0]=(__bf16)v.x; o[1]=(__bf16)v.y; o[2]=(__bf16)v.z; o[3]=(__bf16)v.w;
        *(bf16x4v*)(xb + i) = o;
    } else if (bid < 5120) {
        int i = (bid - 4096) * 256 + tid;   // 262144 total
        int b = i >> 17;
        int r = i & 131071;
        float4 kv = ck[i];
        ((float4*)(kout + (size_t)b * S_ * KH * HD))[r] = kv;
        ((float4*)(vout + (size_t)b * S_ * KH * HD))[r] = cv[i];
        int h4 = r & 31;
        int kh = (r >> 5) & 3;
        int s  = r >> 7;
        bf16x4v o; o[0]=(__bf16)kv.x; o[1]=(__bf16)kv.y; o[2]=(__bf16)kv.z; o[3]=(__bf16)kv.w;
        *(bf16x4v*)(kb + (((size_t)(b * KH + kh) * S_ + s) * HD) + h4 * 4) = o;
    } else if (bid < 15360) {
        int b2 = bid - 5120;
        if (b2 < 6144) {
            int zz  = b2 >> 8;
            int rem = b2 & 255;
            int h0 = (rem & 3) * 32;
            int d0 = (rem >> 2) * 32;
            const float* ip = (zz < 16) ? (wq + (size_t)zz * D_ * HD)
                                        : (wkv + (size_t)(zz - 16) * D_ * HD);
            __bf16* op = wt + (size_t)zz * D_ * HD;
            for (int i = 0; i < 32; i += 8)
                tile[ty + i][tx] = ip[(size_t)(d0 + ty + i) * HD + h0 + tx];
            __syncthreads();
            for (int i = 0; i < 32; i += 8)
                op[(size_t)(h0 + ty + i) * D_ + d0 + tx] = (__bf16)tile[tx][ty + i];
        } else {
            int r2  = b2 - 6144;
            int n   = r2 >> 8;
            int rem = r2 & 255;
            int d0 = (rem & 63) * 32;
            int h0 = (rem >> 6) * 32;
            const float* ip = wo + (size_t)n * (HD * D_);
            for (int i = 0; i < 32; i += 8)
                tile[ty + i][tx] = ip[(size_t)(h0 + ty + i) * D_ + d0 + tx];
            __syncthreads();
            for (int i = 0; i < 32; i += 8)
                wot[(size_t)(d0 + ty + i) * (NH * HD) + n * HD + h0 + tx] = (__bf16)tile[tx][ty + i];
        }
    } else {
        // cache-V transpose: 1024 blocks = 8 (b,kh) x 32 s-tiles x 4 h-tiles
        int c = bid - 15360;
        int z = c >> 7;               // b*KH + kh
        int rem = c & 127;
        int h0 = (rem & 3) * 32;
        int s0 = (rem >> 2) * 32;     // s in [0, TC)
        int b = z >> 2, kh = z & 3;
        const float* ip = (const float*)cv + ((size_t)b * TC_ * KH + kh) * HD;
        for (int i = 0; i < 32; i += 8)
            tile[ty + i][tx] = ip[(size_t)(s0 + ty + i) * (KH * HD) + h0 + tx];
        __syncthreads();
        __bf16* op = vtb + ((size_t)(b * KH + kh)) * (size_t)HD * S_;
        for (int i = 0; i < 32; i += 8)
            op[(size_t)(h0 + ty + i) * S_ + s0 + tx] = (__bf16)tile[tx][ty + i];
    }
}

// ---------------- QKV GEMM with fused RoPE/scatter epilogue (XCD-swizzled) ---------
// 1-D grid of 384 blocks; swz = (bid%8)*48 + bid/8 keeps each XCD on a contiguous
// run of m-tiles (same B-panel reused within one XCD's L2).
// V epilogue also writes the NEW half of vtb directly (transposed): per (i,j) each
// lane's 4 acc values are 4 consecutive t for fixed h -> aligned bf16x4 store.
__global__ __launch_bounds__(256, 2)
void gemm_qkv(const __bf16* __restrict__ A, const __bf16* __restrict__ BT,
              const int* __restrict__ pos, __bf16* __restrict__ qws,
              float* __restrict__ kout, float* __restrict__ vout,
              __bf16* __restrict__ kb, __bf16* __restrict__ vtb) {
    __shared__ __bf16 As[128 * 64];
    __shared__ __bf16 Bs[128 * 64];
    const int swz = (blockIdx.x & 7) * 48 + (blockIdx.x >> 3);
    const int m0 = (swz & 15) * 128;
    const int head = swz >> 4;
    const int n0 = head * 128;
    const int tid = threadIdx.x;
    const int wave = tid >> 6, lane = tid & 63;
    const int quad = lane >> 4, l16 = lane & 15;
    const int wm = (wave & 1) * 64;
    const int bn0 = (wave >> 1) * 32;          // n-slot base for this wave
    const int lrow = lane >> 3;
    const int lsw  = (lane & 7) ^ (lrow & 7);

    f32x4v acc[4][4];
    for (int i = 0; i < 4; i++)
        for (int j = 0; j < 4; j++)
            acc[i][j] = (f32x4v){0.f, 0.f, 0.f, 0.f};

    const __bf16* Abase = A + (size_t)m0 * D_;
    const __bf16* Bbase = BT + (size_t)n0 * D_;

    for (int k0 = 0; k0 < D_; k0 += 64) {
        for (int j = 0; j < 4; j++) {
            int r = wave * 32 + j * 8;
            async_copy16(As + (size_t)r * 64,
                         Abase + (size_t)(r + lrow) * D_ + k0 + lsw * 8);
            async_copy16(Bs + (size_t)r * 64,
                         Bbase + (size_t)(r + lrow) * D_ + k0 + lsw * 8);
        }
        __syncthreads();
        for (int ks = 0; ks < 2; ks++) {
            const int ch = ((ks * 4 + quad) ^ (l16 & 7)) * 8;
            bf16x8v a[4], b[4];
            for (int i = 0; i < 4; i++)
                a[i] = *(const bf16x8v*)(As + (wm + i * 16 + l16) * 64 + ch);
            for (int j = 0; j < 4; j++) {
                int bn = bn0 + (j >> 1) * 16 + (j & 1) * 64;
                b[j] = *(const bf16x8v*)(Bs + (bn + l16) * 64 + ch);
            }
            for (int i = 0; i < 4; i++)
                for (int j = 0; j < 4; j++)
                    acc[i][j] = __builtin_amdgcn_mfma_f32_16x16x32_bf16(a[i], b[j], acc[i][j], 0, 0, 0);
        }
        __syncthreads();
    }

    const float RFREQ = 9.210340371976184f / 64.0f;   // ln(1e4)/64
    const float qscale = 0.08838834764831845f;        // 128^-0.5

    if (head < NH) {
        for (int i = 0; i < 4; i++)
            for (int r = 0; r < 4; r++) {
                int row = m0 + wm + i * 16 + quad * 4 + r;
                float p = (float)pos[row];
                size_t qo = ((size_t)row * NH + head) * HD;
                for (int jp = 0; jp < 2; jp++) {
                    int hh = bn0 + jp * 16 + l16;
                    float ang = p * __expf(-(float)hh * RFREQ);
                    float sn, cs; __sincosf(ang, &sn, &cs);
                    float x1 = acc[i][jp * 2][r], x2 = acc[i][jp * 2 + 1][r];
                    qws[qo + hh]      = (__bf16)((x1 * cs - x2 * sn) * qscale);
                    qws[qo + hh + 64] = (__bf16)((x2 * cs + x1 * sn) * qscale);
                }
            }
    } else if (head < NH + KH) {
        int kh = head - NH;
        for (int i = 0; i < 4; i++)
            for (int r = 0; r < 4; r++) {
                int row = m0 + wm + i * 16 + quad * 4 + r;
                int b = row >> 10, t = row & 1023;
                float p = (float)pos[row];
                size_t ko  = ((size_t)(b * S_ + TC_ + t) * KH + kh) * HD;
                size_t kbo = ((size_t)(b * KH + kh) * S_ + TC_ + t) * HD;
                for (int jp = 0; jp < 2; jp++) {
                    int hh = bn0 + jp * 16 + l16;
                    float ang = p * __expf(-(float)hh * RFREQ);
                    float sn, cs; __sincosf(ang, &sn, &cs);
                    float x1 = acc[i][jp * 2][r], x2 = acc[i][jp * 2 + 1][r];
                    float k1 = x1 * cs - x2 * sn, k2 = x2 * cs + x1 * sn;
                    kout[ko + hh]      = k1;
                    kout[ko + hh + 64] = k2;
                    kb[kbo + hh]      = (__bf16)k1;
                    kb[kbo + hh + 64] = (__bf16)k2;
                }
            }
    } else {
        int kh = head - NH - KH;
        for (int i = 0; i < 4; i++) {
            int row0 = m0 + wm + i * 16 + quad * 4;     // 4 consecutive t from here
            int b0 = row0 >> 10, tb = row0 & 1023;
            for (int r = 0; r < 4; r++) {
                int row = row0 + r;
                int b = row >> 10, t = row & 1023;
                size_t vo = ((size_t)(b * S_ + TC_ + t) * KH + kh) * HD;
                for (int j = 0; j < 4; j++) {
                    int h = bn0 + (j >> 1) * 16 + (j & 1) * 64 + l16;
                    vout[vo + h] = acc[i][j][r];
                }
            }
            // transposed bf16 write into vtb (new half): h fixed, t consecutive
            for (int j = 0; j < 4; j++) {
                int h = bn0 + (j >> 1) * 16 + (j & 1) * 64 + l16;
                bf16x4v tv;
                for (int r = 0; r < 4; r++) tv[r] = (__bf16)acc[i][j][r];
                *(bf16x4v*)(vtb + ((size_t)(b0 * KH + kh) * HD + h) * S_ + TC_ + tb) = tv;
            }
        }
    }
}

// ---------------- 128x128-tile bf16 GEMM, C = A @ BT^T (XCD-swizzled) ----------------
__global__ __launch_bounds__(256, 2)
void gemm_bt(const __bf16* __restrict__ A, const __bf16* __restrict__ BT,
             float* __restrict__ C, int ldc) {
    __shared__ __bf16 As[128 * 64];
    __shared__ __bf16 Bs[128 * 64];
    const int swz = (blockIdx.x & 7) * 32 + (blockIdx.x >> 3);
    const int m0 = (swz & 15) * 128, n0 = (swz >> 4) * 128;
    const int tid = threadIdx.x;
    const int wave = tid >> 6, lane = tid & 63;
    const int quad = lane >> 4, l16 = lane & 15;
    const int wm = (wave & 1) * 64, wn = (wave >> 1) * 64;
    const int lrow = lane >> 3;
    const int lsw  = (lane & 7) ^ (lrow & 7);

    f32x4v acc[4][4];
    for (int i = 0; i < 4; i++)
        for (int j = 0; j < 4; j++)
            acc[i][j] = (f32x4v){0.f, 0.f, 0.f, 0.f};

    const __bf16* Abase = A + (size_t)m0 * D_;
    const __bf16* Bbase = BT + (size_t)n0 * D_;

    for (int k0 = 0; k0 < D_; k0 += 64) {
        for (int j = 0; j < 4; j++) {
            int r = wave * 32 + j * 8;
            async_copy16(As + (size_t)r * 64,
                         Abase + (size_t)(r + lrow) * D_ + k0 + lsw * 8);
            async_copy16(Bs + (size_t)r * 64,
                         Bbase + (size_t)(r + lrow) * D_ + k0 + lsw * 8);
        }
        __syncthreads();
        for (int ks = 0; ks < 2; ks++) {
            const int ch = ((ks * 4 + quad) ^ (l16 & 7)) * 8;
            bf16x8v a[4], b[4];
            for (int i = 0; i < 4; i++)
                a[i] = *(const bf16x8v*)(As + (wm + i * 16 + l16) * 64 + ch);
            for (int j = 0; j < 4; j++)
                b[j] = *(const bf16x8v*)(Bs + (wn + j * 16 + l16) * 64 + ch);
            for (int i = 0; i < 4; i++)
                for (int j = 0; j < 4; j++)
                    acc[i][j] = __builtin_amdgcn_mfma_f32_16x16x32_bf16(a[i], b[j], acc[i][j], 0, 0, 0);
        }
        __syncthreads();
    }
    for (int i = 0; i < 4; i++)
        for (int j = 0; j < 4; j++)
            for (int r = 0; r < 4; r++) {
                int row = m0 + wm + i * 16 + quad * 4 + r;
                int col = n0 + wn + j * 16 + l16;
                C[(size_t)row * ldc + col] = acc[i][j][r];
            }
}

// ---------------- flash attention (8 waves, XOR-swizzled LDS) — round-1 proven ----
__global__ __launch_bounds__(512, 1)
void attn(const __bf16* __restrict__ qws, const __bf16* __restrict__ kb,
          const __bf16* __restrict__ vtb, __bf16* __restrict__ enc) {
    __shared__ __bf16 Qs[128 * 128];
    __shared__ __bf16 Ks[128 * 128];
    __shared__ __bf16 Vs[128 * 128];
    __shared__ __bf16 Ps[128 * 128];

    const int t0 = blockIdx.x * 128;
    const int n  = blockIdx.y;
    const int b  = blockIdx.z;
    const int kh = n / (NH / KH);
    const int tid = threadIdx.x, wave = tid >> 6, lane = tid & 63;
    const int quad = lane >> 4, l16 = lane & 15;
    const int wm = wave * 16;
    const int arow = lane >> 4;
    const int acol = lane & 15;

    // Q tile [128 t][128 h], swizzled source
    {
        const __bf16* qtile = qws + ((size_t)(b * T_ + t0) * NH + n) * HD;
        for (int jj = 0; jj < 4; jj++) {
            int r0 = wm + jj * 4;
            int row = r0 + arow;
            async_copy16(Qs + (size_t)r0 * 128,
                         qtile + (size_t)row * (NH * HD) + ((acol ^ (row & 15)) * 8));
        }
    }

    float m_run[4], l_run[4];
    f32x4v o_acc[8];
    for (int r = 0; r < 4; r++) { m_run[r] = -INFINITY; l_run[r] = 0.f; }
    for (int j = 0; j < 8; j++) o_acc[j] = (f32x4v){0.f, 0.f, 0.f, 0.f};

    const int nS = (TC_ + t0 + 128) >> 7;
    const __bf16* kbase = kb  + ((size_t)(b * KH + kh)) * S_ * HD;
    const __bf16* vbase = vtb + ((size_t)(b * KH + kh)) * (size_t)HD * S_;

    for (int st = 0; st < nS; st++) {
        const int s0 = st * 128;
        {
            const __bf16* ktile = kbase + (size_t)s0 * HD;
            for (int jj = 0; jj < 4; jj++) {
                int r0 = wm + jj * 4;
                int row = r0 + arow;
                async_copy16(Ks + (size_t)r0 * 128,
                             ktile + (size_t)row * HD + ((acol ^ (row & 15)) * 8));
            }
        }
        {
            const __bf16* vtile = vbase + s0;
            for (int jj = 0; jj < 4; jj++) {
                int r0 = wm + jj * 4;
                int row = r0 + arow;
                async_copy16(Vs + (size_t)r0 * 128,
                             vtile + (size_t)row * S_ + ((acol ^ (row & 15)) * 8));
            }
        }
        __syncthreads();

        // QK^T: this wave's 16 rows x 128 cols
        f32x4v sc[8];
        for (int j = 0; j < 8; j++) sc[j] = (f32x4v){0.f, 0.f, 0.f, 0.f};
        for (int ks = 0; ks < 4; ks++) {
            int ch = (ks * 4 + quad) ^ l16;
            bf16x8v a = *(const bf16x8v*)(Qs + (wm + l16) * 128 + ch * 8);
            bf16x8v bb[8];
            for (int j = 0; j < 8; j++)
                bb[j] = *(const bf16x8v*)(Ks + (j * 16 + l16) * 128 + ch * 8);
            for (int j = 0; j < 8; j++)
                sc[j] = __builtin_amdgcn_mfma_f32_16x16x32_bf16(a, bb[j], sc[j], 0, 0, 0);
        }

        // causal mask (diagonal tile only: s0 == TC + t0)
        if (st == nS - 1) {
            for (int j = 0; j < 8; j++)
                for (int r = 0; r < 4; r++) {
                    int row = wm + quad * 4 + r;
                    int col = j * 16 + l16;
                    if (col > row) sc[j][r] = -3.0e38f;
                }
        }

        // online softmax
        for (int r = 0; r < 4; r++) {
            float mx = sc[0][r];
            for (int j = 1; j < 8; j++) mx = fmaxf(mx, sc[j][r]);
            for (int off = 8; off >= 1; off >>= 1) mx = fmaxf(mx, __shfl_xor(mx, off, 64));
            mx = fmaxf(mx, m_run[r]);
            float alpha = __expf(m_run[r] - mx);
            m_run[r] = mx;
            float s = 0.f;
            for (int j = 0; j < 8; j++) {
                float pv = __expf(sc[j][r] - mx);
                sc[j][r] = pv;
                s += pv;
            }
            for (int off = 8; off >= 1; off >>= 1) s += __shfl_xor(s, off, 64);
            l_run[r] = l_run[r] * alpha + s;
            for (int j = 0; j < 8; j++) o_acc[j][r] *= alpha;
        }

        // P -> LDS (C-layout -> A-layout), swizzled chunks
        for (int j = 0; j < 8; j++)
            for (int r = 0; r < 4; r++) {
                int row = wm + quad * 4 + r;
                int c = (j * 2 + (l16 >> 3)) ^ (row & 15);
                Ps[row * 128 + c * 8 + (l16 & 7)] = (__bf16)sc[j][r];
            }
        __syncthreads();

        // PV: o_acc += P @ V
        for (int ks = 0; ks < 4; ks++) {
            int ch = (ks * 4 + quad) ^ l16;
            bf16x8v a = *(const bf16x8v*)(Ps + (wm + l16) * 128 + ch * 8);
            bf16x8v bb[8];
            for (int j = 0; j < 8; j++)
                bb[j] = *(const bf16x8v*)(Vs + (j * 16 + l16) * 128 + ch * 8);
            for (int j = 0; j < 8; j++)
                o_acc[j] = __builtin_amdgcn_mfma_f32_16x16x32_bf16(a, bb[j], o_acc[j], 0, 0, 0);
        }
        __syncthreads();
    }

    // epilogue: enc[b,t,n,h] bf16
    for (int r = 0; r < 4; r++) {
        float inv = 1.0f / l_run[r];
        int row = wm + quad * 4 + r;
        for (int j = 0; j < 8; j++) {
            int col = j * 16 + l16;
            enc[((size_t)(b * T_ + t0 + row) * NH + n) * HD + col] =
                (__bf16)(o_acc[j][r] * inv);
        }
    }
}

extern "C" void kernel_launch(void* const* d_in, const int* in_sizes, int n_in,
                              void* d_out, int out_size, void* d_ws, size_t ws_size,
                              hipStream_t stream) {
    const float* x       = (const float*)d_in[0];
    const int*   pos     = (const int*)d_in[1];
    const float* cache_k = (const float*)d_in[3];
    const float* cache_v = (const float*)d_in[4];
    const float* w_q     = (const float*)d_in[5];
    const float* w_kv    = (const float*)d_in[6];
    const float* w_out   = (const float*)d_in[7];

    float* out  = (float*)d_out;
    float* kout = out  + (size_t)B_ * T_ * D_;
    float* vout = kout + (size_t)B_ * S_ * KH * HD;

    char* ws = (char*)d_ws;
    __bf16* xb   = (__bf16*)ws;  ws += (size_t)B_ * T_ * D_ * 2;
    __bf16* wt   = (__bf16*)ws;  ws += (size_t)3072 * D_ * 2;
    __bf16* wot  = (__bf16*)ws;  ws += (size_t)D_ * NH * HD * 2;
    __bf16* qws  = (__bf16*)ws;  ws += (size_t)B_ * T_ * NH * HD * 2;
    __bf16* kbuf = (__bf16*)ws;  ws += (size_t)B_ * S_ * KH * HD * 2;
    __bf16* vtb  = (__bf16*)ws;  ws += (size_t)B_ * S_ * KH * HD * 2;
    __bf16* enc  = (__bf16*)ws;

    prep_all<<<16384, dim3(32, 8), 0, stream>>>(x, xb, (const float4*)cache_k,
                                                (const float4*)cache_v, kout, vout, kbuf,
                                                w_q, w_kv, w_out, wt, wot, vtb);
    gemm_qkv<<<384, 256, 0, stream>>>(xb, wt, pos, qws, kout, vout, kbuf, vtb);
    attn<<<dim3(8, 16, 2), 512, 0, stream>>>(qws, kbuf, vtb, enc);
    gemm_bt<<<256, 256, 0, stream>>>(enc, wot, out, 2048);
}